// Round 16
// baseline (44.501 us; speedup 1.0000x reference)
//
#include <hip/hip_runtime.h>

// MesoLayer R15: R14 (41.0us: reg-staged 2-deep + DPP quad_perm reduces)
// with WAITC+WRITE hoisted BEFORE COMPUTE so the 7x ds_write_b128 drain
// overlaps compute instead of sitting naked before the barrier.
// Phase p: FLUSH(p-1) -> ISSUE(p+2) -> WAITC(p+1, free) -> WRITE(p+1) ->
//          COMPUTE(p) -> lgkm0 + barrier.
// Legality: barrier at end of p-1 guarantees all waves drained their reads
// of the WRITE target buffer (R9 invariant). WAITC audit unchanged by the
// hoist: steady (7,8); p=0 (6,7); p=14 (1,1).

static __device__ __forceinline__ float dpp_xor1(float a) {
  return __int_as_float(__builtin_amdgcn_mov_dpp(
      __float_as_int(a), 0xB1, 0xF, 0xF, false));  // quad_perm [1,0,3,2]
}
static __device__ __forceinline__ float dpp_xor2(float a) {
  return __int_as_float(__builtin_amdgcn_mov_dpp(
      __float_as_int(a), 0x4E, 0xF, 0xF, false));  // quad_perm [2,3,0,1]
}
static __device__ __forceinline__ float xsum(float a) {
  a += dpp_xor1(a);
  a += dpp_xor2(a);
  return a;
}
static __device__ __forceinline__ float xmax(float a) {
  a = fmaxf(a, dpp_xor1(a));
  a = fmaxf(a, dpp_xor2(a));
  return a;
}

// 64-lane segment: lane (q=ln&3, r=ln>>2) covers row r, j in {q, q+4, ...};
// reduce over q via DPP quad_perm; true global max -> single-pass exp.
// Mt = upper-tri of M = W W^T.
template<int L, int SEGOFF, int OUTOFF>
__device__ __forceinline__ void seg64(const float* __restrict__ bp, int q,
                                      const float (&Mt)[15],
                                      float* __restrict__ ob) {
  constexpr int T[5][5] = {{0, 1, 2, 3, 4},  {1, 5, 6, 7, 8},
                           {2, 6, 9, 10, 11}, {3, 7, 10, 12, 13},
                           {4, 8, 11, 13, 14}};
  constexpr int NJ = (L + 3) / 4;
  const bool lastv = (q + 4 * (NJ - 1)) < L;

  float s[NJ][5];
#pragma unroll
  for (int k = 0; k < NJ; ++k) {
    int j = q + 4 * k;
    if (j > L - 1) j = L - 1;  // only last k can clamp
#pragma unroll
    for (int g = 0; g < 5; ++g) s[k][g] = bp[SEGOFF + j * 5 + g];
  }
#pragma unroll
  for (int g = 0; g < 5; ++g) s[NJ - 1][g] = lastv ? s[NJ - 1][g] : 0.f;

  float ssl[5];
#pragma unroll
  for (int g = 0; g < 5; ++g) {
    float a = s[0][g];
#pragma unroll
    for (int k = 1; k < NJ; ++k) a += s[k][g];
    ssl[g] = xsum(a);  // full subsum on all lanes
  }

  float v[5];
#pragma unroll
  for (int g = 0; g < 5; ++g) {
    float a = Mt[T[g][0]] * ssl[0];
#pragma unroll
    for (int h = 1; h < 5; ++h) a += Mt[T[g][h]] * ssl[h];
    v[g] = a;
  }

  float sc[NJ];
#pragma unroll
  for (int k = 0; k < NJ; ++k) {
    float a = s[k][0] * v[0];
#pragma unroll
    for (int g = 1; g < 5; ++g) a += s[k][g] * v[g];
    sc[k] = a;
  }
  sc[NJ - 1] = lastv ? sc[NJ - 1] : -3.0e38f;

  float ml = sc[0];
#pragma unroll
  for (int k = 1; k < NJ; ++k) ml = fmaxf(ml, sc[k]);
  float m = xmax(ml);

  float d = 0.f, pl[5] = {0.f, 0.f, 0.f, 0.f, 0.f};
#pragma unroll
  for (int k = 0; k < NJ; ++k) {
    float e = __expf(sc[k] - m);  // masked k: exp(-huge)=0
    d += e;
#pragma unroll
    for (int g = 0; g < 5; ++g) pl[g] += e * s[k][g];
  }
  d = xsum(d);
  float inv = 1.0f / d;
#pragma unroll
  for (int g = 0; g < 5; ++g) pl[g] = xsum(pl[g]);
  if (q == 0) {
#pragma unroll
    for (int g = 0; g < 5; ++g) ob[OUTOFF + g] = pl[g] * inv;
  }
}

// LDS (float4 units): buf0 [0,1560) | buf1 [1560,3120) | outbuf [3120,3400)
// = 54.4 KB -> 2 blocks/CU.
__global__ __launch_bounds__(256, 2) void meso_kernel(
    const float* __restrict__ x, const float* __restrict__ w,
    float* __restrict__ out) {
  __shared__ __align__(16) float4 sm4[3400];
  float* smf = (float*)sm4;
  const int t = threadIdx.x;
  const int wv = t >> 6, ln = t & 63, q = ln & 3, r = ln >> 2;
  const size_t blk = blockIdx.x;
  const float4* xp4 = (const float4*)x + blk * 24960;  // 256*390/4
  float4* o4 = (float4*)out + blk * 2240;              // 256*35/4

  float4 A0, A1, A2, A3, A4, A5, A6 = make_float4(0, 0, 0, 0);
  float4 B0, B1, B2, B3, B4, B5, B6 = make_float4(0, 0, 0, 0);

  // Stage-issue chunk c into reg set (6 full loads + wave3 tail of 24).
#define ISSUE(R, c)                                                    \
  { const float4* g_ = xp4 + (size_t)(c) * 1560;                       \
    R##0 = g_[t];        R##1 = g_[t + 256];  R##2 = g_[t + 512];      \
    R##3 = g_[t + 768];  R##4 = g_[t + 1024]; R##5 = g_[t + 1280];     \
    if (t >= 232) R##6 = g_[1304 + t]; }

#define WRITE(R, b)                                                    \
  { float4* l_ = sm4 + (b) * 1560;                                     \
    l_[t] = R##0;        l_[t + 256] = R##1;  l_[t + 512] = R##2;      \
    l_[t + 768] = R##3;  l_[t + 1024] = R##4; l_[t + 1280] = R##5;     \
    if (t >= 232) l_[1304 + t] = R##6; }

  // n = #VMEM ops this wave issued after the awaited chunk's last load
  // (wave3 carries the 24-lane tail -> 7 loads/chunk vs 6).
#define WAITC(n03, n3)                                                 \
  { if (wv == 3) asm volatile("s_waitcnt vmcnt(" #n3 ")" ::: "memory");\
    else         asm volatile("s_waitcnt vmcnt(" #n03 ")" ::: "memory"); }

#define BAR()                                                          \
  { asm volatile("s_waitcnt lgkmcnt(0)" ::: "memory");                 \
    __builtin_amdgcn_s_barrier();                                      \
    __builtin_amdgcn_sched_barrier(0); }

#define FLUSH(pp)                                                      \
  { if (ln < 35)                                                       \
      o4[(size_t)(pp) * 140 + wv * 35 + ln] =                          \
          sm4[3120 + ((pp) & 1) * 140 + wv * 35 + ln]; }

#define COMPUTE(par)                                                   \
  { const float* bp = smf + (par) * 6240 + r * 390;                    \
    float* ob = smf + 12480 + (par) * 560 + r * 35;                    \
    if (wv == 0) { seg64<25, 115, 15>(bp, q, Mt, ob); }                \
    else if (wv == 1) { seg64<12, 330, 30>(bp, q, Mt, ob);             \
                        seg64<5,  0,   0 >(bp, q, Mt, ob); }           \
    else if (wv == 2) { seg64<9,  25,  5 >(bp, q, Mt, ob);             \
                        seg64<9,  70,  10>(bp, q, Mt, ob); }           \
    else              { seg64<9,  240, 20>(bp, q, Mt, ob);             \
                        seg64<9,  285, 25>(bp, q, Mt, ob); } }

  ISSUE(A, 0)
  ISSUE(B, 1)

  // Mt = upper-tri(W W^T) from uniform scalar loads, overlapping load latency.
  float Mt[15];
  {
    int i = 0;
#pragma unroll
    for (int g = 0; g < 5; ++g)
#pragma unroll
      for (int h = g; h < 5; ++h, ++i) {
        float a = 0.f;
#pragma unroll
        for (int k = 0; k < 10; ++k) a += w[g * 10 + k] * w[h * 10 + k];
        Mt[i] = a;
      }
  }

  WAITC(6, 7)      // chunk0 complete (newer = chunk1's 6/7 loads)
  WRITE(A, 0)
  BAR()

#pragma unroll 1
  for (int p = 0; p < 16; p += 2) {
    // ---- even phase p: compute buf0/out0; B holds chunk p+1 (landed) ----
    if (p > 0) FLUSH(p - 1)
    if (p + 2 < 16) ISSUE(A, p + 2)
    if (p == 0)       WAITC(6, 7)   // newer = issue(p+2) only
    else if (p < 14)  WAITC(7, 8)   // newer = flush store + issue(p+2)
    else              WAITC(1, 1)   // p=14: newer = flush store only
    WRITE(B, 1)                     // overlaps with COMPUTE below
    COMPUTE(0)
    BAR()

    // ---- odd phase p+1: compute buf1/out1; A holds chunk p+2 ----
    FLUSH(p)
    if (p + 3 < 16) ISSUE(B, p + 3)
    if (p + 2 < 16) {
      WAITC(7, 8)                   // newer = flush store + issue(p+3)
      WRITE(A, 0)
    }
    COMPUTE(1)
    BAR()
  }
  FLUSH(15)
}

extern "C" void kernel_launch(void* const* d_in, const int* in_sizes, int n_in,
                              void* d_out, int out_size, void* d_ws, size_t ws_size,
                              hipStream_t stream) {
  const float* x = (const float*)d_in[0];
  const float* w = (const float*)d_in[1];
  float* out = (float*)d_out;
  int B = in_sizes[0] / 390;  // 131072
  int grid = B / 256;         // 512 blocks = 2/CU, all resident
  meso_kernel<<<grid, 256, 0, stream>>>(x, w, out);
}

// Round 17
// 41.276 us; speedup vs baseline: 1.0781x; 1.0781x over previous
//
#include <hip/hip_runtime.h>

// MesoLayer R16: exact revert to R14 (best, 41.0us) with one change: no
// sched_barrier(0) after the phase barrier (barrier + "memory"-clobbered
// waitcnts already order everything; freeing the scheduler lets it overlap
// address math across phase boundaries).
// Block = 256 threads = 256 rows, 16 chunks x 16 rows (1560 float4 flat).
// Phase p: FLUSH(p-1) -> ISSUE(chunk p+2) -> COMPUTE(p) -> WAITC(chunk p+1)
// -> WRITE -> lgkm0+barrier. Reduces via forced DPP quad_perm (VALU pipe).

static __device__ __forceinline__ float dpp_xor1(float a) {
  return __int_as_float(__builtin_amdgcn_mov_dpp(
      __float_as_int(a), 0xB1, 0xF, 0xF, false));  // quad_perm [1,0,3,2]
}
static __device__ __forceinline__ float dpp_xor2(float a) {
  return __int_as_float(__builtin_amdgcn_mov_dpp(
      __float_as_int(a), 0x4E, 0xF, 0xF, false));  // quad_perm [2,3,0,1]
}
static __device__ __forceinline__ float xsum(float a) {
  a += dpp_xor1(a);
  a += dpp_xor2(a);
  return a;
}
static __device__ __forceinline__ float xmax(float a) {
  a = fmaxf(a, dpp_xor1(a));
  a = fmaxf(a, dpp_xor2(a));
  return a;
}

// 64-lane segment: lane (q=ln&3, r=ln>>2) covers row r, j in {q, q+4, ...};
// reduce over q via DPP quad_perm; true global max -> single-pass exp.
// Mt = upper-tri of M = W W^T.
template<int L, int SEGOFF, int OUTOFF>
__device__ __forceinline__ void seg64(const float* __restrict__ bp, int q,
                                      const float (&Mt)[15],
                                      float* __restrict__ ob) {
  constexpr int T[5][5] = {{0, 1, 2, 3, 4},  {1, 5, 6, 7, 8},
                           {2, 6, 9, 10, 11}, {3, 7, 10, 12, 13},
                           {4, 8, 11, 13, 14}};
  constexpr int NJ = (L + 3) / 4;
  const bool lastv = (q + 4 * (NJ - 1)) < L;

  float s[NJ][5];
#pragma unroll
  for (int k = 0; k < NJ; ++k) {
    int j = q + 4 * k;
    if (j > L - 1) j = L - 1;  // only last k can clamp
#pragma unroll
    for (int g = 0; g < 5; ++g) s[k][g] = bp[SEGOFF + j * 5 + g];
  }
#pragma unroll
  for (int g = 0; g < 5; ++g) s[NJ - 1][g] = lastv ? s[NJ - 1][g] : 0.f;

  float ssl[5];
#pragma unroll
  for (int g = 0; g < 5; ++g) {
    float a = s[0][g];
#pragma unroll
    for (int k = 1; k < NJ; ++k) a += s[k][g];
    ssl[g] = xsum(a);  // full subsum on all lanes
  }

  float v[5];
#pragma unroll
  for (int g = 0; g < 5; ++g) {
    float a = Mt[T[g][0]] * ssl[0];
#pragma unroll
    for (int h = 1; h < 5; ++h) a += Mt[T[g][h]] * ssl[h];
    v[g] = a;
  }

  float sc[NJ];
#pragma unroll
  for (int k = 0; k < NJ; ++k) {
    float a = s[k][0] * v[0];
#pragma unroll
    for (int g = 1; g < 5; ++g) a += s[k][g] * v[g];
    sc[k] = a;
  }
  sc[NJ - 1] = lastv ? sc[NJ - 1] : -3.0e38f;

  float ml = sc[0];
#pragma unroll
  for (int k = 1; k < NJ; ++k) ml = fmaxf(ml, sc[k]);
  float m = xmax(ml);

  float d = 0.f, pl[5] = {0.f, 0.f, 0.f, 0.f, 0.f};
#pragma unroll
  for (int k = 0; k < NJ; ++k) {
    float e = __expf(sc[k] - m);  // masked k: exp(-huge)=0
    d += e;
#pragma unroll
    for (int g = 0; g < 5; ++g) pl[g] += e * s[k][g];
  }
  d = xsum(d);
  float inv = 1.0f / d;
#pragma unroll
  for (int g = 0; g < 5; ++g) pl[g] = xsum(pl[g]);
  if (q == 0) {
#pragma unroll
    for (int g = 0; g < 5; ++g) ob[OUTOFF + g] = pl[g] * inv;
  }
}

// LDS (float4 units): buf0 [0,1560) | buf1 [1560,3120) | outbuf [3120,3400)
// = 54.4 KB -> 2 blocks/CU.
__global__ __launch_bounds__(256, 2) void meso_kernel(
    const float* __restrict__ x, const float* __restrict__ w,
    float* __restrict__ out) {
  __shared__ __align__(16) float4 sm4[3400];
  float* smf = (float*)sm4;
  const int t = threadIdx.x;
  const int wv = t >> 6, ln = t & 63, q = ln & 3, r = ln >> 2;
  const size_t blk = blockIdx.x;
  const float4* xp4 = (const float4*)x + blk * 24960;  // 256*390/4
  float4* o4 = (float4*)out + blk * 2240;              // 256*35/4

  float4 A0, A1, A2, A3, A4, A5, A6 = make_float4(0, 0, 0, 0);
  float4 B0, B1, B2, B3, B4, B5, B6 = make_float4(0, 0, 0, 0);

  // Stage-issue chunk c into reg set (6 full loads + wave3 tail of 24).
#define ISSUE(R, c)                                                    \
  { const float4* g_ = xp4 + (size_t)(c) * 1560;                       \
    R##0 = g_[t];        R##1 = g_[t + 256];  R##2 = g_[t + 512];      \
    R##3 = g_[t + 768];  R##4 = g_[t + 1024]; R##5 = g_[t + 1280];     \
    if (t >= 232) R##6 = g_[1304 + t]; }

#define WRITE(R, b)                                                    \
  { float4* l_ = sm4 + (b) * 1560;                                     \
    l_[t] = R##0;        l_[t + 256] = R##1;  l_[t + 512] = R##2;      \
    l_[t + 768] = R##3;  l_[t + 1024] = R##4; l_[t + 1280] = R##5;     \
    if (t >= 232) l_[1304 + t] = R##6; }

  // n = #VMEM ops this wave issued after the awaited chunk's last load
  // (wave3 carries the 24-lane tail -> 7 loads/chunk vs 6).
#define WAITC(n03, n3)                                                 \
  { if (wv == 3) asm volatile("s_waitcnt vmcnt(" #n3 ")" ::: "memory");\
    else         asm volatile("s_waitcnt vmcnt(" #n03 ")" ::: "memory"); }

#define BAR()                                                          \
  { asm volatile("s_waitcnt lgkmcnt(0)" ::: "memory");                 \
    __builtin_amdgcn_s_barrier(); }

#define FLUSH(pp)                                                      \
  { if (ln < 35)                                                       \
      o4[(size_t)(pp) * 140 + wv * 35 + ln] =                          \
          sm4[3120 + ((pp) & 1) * 140 + wv * 35 + ln]; }

#define COMPUTE(par)                                                   \
  { const float* bp = smf + (par) * 6240 + r * 390;                    \
    float* ob = smf + 12480 + (par) * 560 + r * 35;                    \
    if (wv == 0) { seg64<25, 115, 15>(bp, q, Mt, ob); }                \
    else if (wv == 1) { seg64<12, 330, 30>(bp, q, Mt, ob);             \
                        seg64<5,  0,   0 >(bp, q, Mt, ob); }           \
    else if (wv == 2) { seg64<9,  25,  5 >(bp, q, Mt, ob);             \
                        seg64<9,  70,  10>(bp, q, Mt, ob); }           \
    else              { seg64<9,  240, 20>(bp, q, Mt, ob);             \
                        seg64<9,  285, 25>(bp, q, Mt, ob); } }

  ISSUE(A, 0)
  ISSUE(B, 1)

  // Mt = upper-tri(W W^T) from uniform scalar loads, overlapping load latency.
  float Mt[15];
  {
    int i = 0;
#pragma unroll
    for (int g = 0; g < 5; ++g)
#pragma unroll
      for (int h = g; h < 5; ++h, ++i) {
        float a = 0.f;
#pragma unroll
        for (int k = 0; k < 10; ++k) a += w[g * 10 + k] * w[h * 10 + k];
        Mt[i] = a;
      }
  }

  WAITC(6, 7)      // chunk0 complete (newer = chunk1's 6/7 loads)
  WRITE(A, 0)
  BAR()

#pragma unroll 1
  for (int p = 0; p < 16; p += 2) {
    // ---- even phase p: compute buf0/out0; B holds chunk p+1 ----
    if (p > 0) FLUSH(p - 1)
    if (p + 2 < 16) ISSUE(A, p + 2)
    COMPUTE(0)
    if (p == 0)       WAITC(6, 7)   // newer = issue(p+2) only
    else if (p < 14)  WAITC(7, 8)   // newer = flush store + issue(p+2)
    else              WAITC(1, 1)   // p=14: newer = flush store only
    WRITE(B, 1)
    BAR()

    // ---- odd phase p+1: compute buf1/out1; A holds chunk p+2 ----
    FLUSH(p)
    if (p + 3 < 16) ISSUE(B, p + 3)
    COMPUTE(1)
    if (p + 2 < 16) {
      if (p + 1 < 14) WAITC(7, 8)
      else            WAITC(1, 1)
      WRITE(A, 0)
    }
    BAR()
  }
  FLUSH(15)
}

extern "C" void kernel_launch(void* const* d_in, const int* in_sizes, int n_in,
                              void* d_out, int out_size, void* d_ws, size_t ws_size,
                              hipStream_t stream) {
  const float* x = (const float*)d_in[0];
  const float* w = (const float*)d_in[1];
  float* out = (float*)d_out;
  int B = in_sizes[0] / 390;  // 131072
  int grid = B / 256;         // 512 blocks = 2/CU, all resident
  meso_kernel<<<grid, 256, 0, stream>>>(x, w, out);
}